// Round 8
// baseline (423.326 us; speedup 1.0000x reference)
//
#include <hip/hip_runtime.h>
#include <math.h>

#define N_NODES 50000
#define N_PAD   50048              // rows padded to multiple of 64
#define N_EDGES 1600000
#define DIM     128
#define RCUT    5.0f
#define NGROUP  (N_PAD / 64)       // 782 groups of 64 nodes
#define NB_PRE  128
#define CH_PRE  (N_EDGES / NB_PRE) // 12500 edges per preprocessing block

typedef __attribute__((ext_vector_type(8))) __bf16 bf16x8;
typedef __attribute__((ext_vector_type(4))) float  f32x4;

// ---------------- bf16 helpers ----------------
__device__ __forceinline__ float bf_lo(unsigned int u) { return __uint_as_float(u << 16); }
__device__ __forceinline__ float bf_hi(unsigned int u) { return __uint_as_float(u & 0xffff0000u); }
__device__ __forceinline__ unsigned short f2bf(float x) {
    unsigned int u = __float_as_uint(x);
    u += 0x7fffu + ((u >> 16) & 1u);   // round-to-nearest-even
    return (unsigned short)(u >> 16);
}

// ---------------- fused: v->bf16 convert + W->MFMA-B fragments ----------------
__global__ __launch_bounds__(256) void prep_kernel(
        const float* __restrict__ v, unsigned short* __restrict__ vb,
        const float* __restrict__ Aw, uint4* __restrict__ wfrag) {
    int b = blockIdx.x;
    if (b < 6250) {
        int i = b * 256 + threadIdx.x;           // exactly N_NODES*DIM/4 = 1.6M
        float4 x = ((const float4*)v)[i];
        uint2 o;
        o.x = (unsigned)f2bf(x.x) | ((unsigned)f2bf(x.y) << 16);
        o.y = (unsigned)f2bf(x.z) | ((unsigned)f2bf(x.w) << 16);
        ((uint2*)vb)[i] = o;
    } else {
        int t = (b - 6250) * 256 + threadIdx.x;  // 0..2047
        int lane = t & 63, nt = (t >> 6) & 7, kk = t >> 9;
        int n  = nt * 16 + (lane & 15);
        int k0 = kk * 32 + (lane >> 4) * 8;
        unsigned short h[8];
        #pragma unroll
        for (int i = 0; i < 8; ++i) h[i] = f2bf(Aw[n * DIM + k0 + i]);
        uint4 o;
        o.x = h[0] | ((unsigned)h[1] << 16); o.y = h[2] | ((unsigned)h[3] << 16);
        o.z = h[4] | ((unsigned)h[5] << 16); o.w = h[6] | ((unsigned)h[7] << 16);
        wfrag[t] = o;
    }
}

// ---------------- per-block group-64 histogram (LDS only) ----------------
__global__ __launch_bounds__(256) void countp_kernel(const int* __restrict__ dst,
                                                     int* __restrict__ partial) {
    __shared__ int h[NGROUP];                    // 3.1 KB
    int b = blockIdx.x, tid = threadIdx.x;
    for (int g = tid; g < NGROUP; g += 256) h[g] = 0;
    __syncthreads();
    int beg = b * CH_PRE, end = beg + CH_PRE;
    for (int i = beg + tid; i < end; i += 256)
        atomicAdd(&h[dst[i] >> 6], 1);           // LDS atomic
    __syncthreads();
    for (int g = tid; g < NGROUP; g += 256) partial[b * NGROUP + g] = h[g];
}

// ---------------- group totals (coalesced over g) ----------------
__global__ __launch_bounds__(256) void ktot_kernel(const int* __restrict__ partial,
                                                   int* __restrict__ gtot) {
    int g = blockIdx.x * 256 + threadIdx.x;
    if (g >= NGROUP) return;
    int s = 0;
    for (int b = 0; b < NB_PRE; ++b) s += partial[b * NGROUP + g];
    gtot[g] = s;
}

// ---------------- exclusive scan over 782 group totals ----------------
__global__ __launch_bounds__(256) void kscan_kernel(const int* __restrict__ gtot,
                                                    int* __restrict__ goff) {
    __shared__ int part[256];
    int tid = threadIdx.x;
    int i0 = tid * 4;
    int v[4]; int s = 0;
    #pragma unroll
    for (int k = 0; k < 4; ++k) { int i = i0 + k; v[k] = (i < NGROUP) ? gtot[i] : 0; s += v[k]; }
    part[tid] = s; __syncthreads();
    for (int d = 1; d < 256; d <<= 1) {
        int val = (tid >= d) ? part[tid - d] : 0;
        __syncthreads(); part[tid] += val; __syncthreads();
    }
    int run = (tid == 0) ? 0 : part[tid - 1];
    #pragma unroll
    for (int k = 0; k < 4; ++k) {
        int i = i0 + k;
        if (i < NGROUP) { goff[i] = run; run += v[k]; }
    }
    if (tid == 0) goff[NGROUP] = N_EDGES;
}

// ---------------- per-(block,group) bases (coalesced over g) ----------------
__global__ __launch_bounds__(256) void kbase_kernel(const int* __restrict__ partial,
                                                    const int* __restrict__ goff,
                                                    int* __restrict__ pbase) {
    int g = blockIdx.x * 256 + threadIdx.x;
    if (g >= NGROUP) return;
    int run = goff[g];
    for (int b = 0; b < NB_PRE; ++b) {
        pbase[b * NGROUP + g] = run;
        run += partial[b * NGROUP + g];
    }
}

// ---------------- reorder into group-64 CSR with 6-bit node tags ----------
// metaT[slot] = { src*256 | (dst&63)<<24, bitcast(f) }
__global__ __launch_bounds__(256) void reorder_kernel(
        const float* __restrict__ e,
        const int*   __restrict__ src,
        const int*   __restrict__ dst,
        const float* __restrict__ rs,
        const float* __restrict__ sigma,
        const int*   __restrict__ pbase,
        int2* __restrict__ metaT) {
    __shared__ int base[NGROUP];
    __shared__ int cnt[NGROUP];
    int b = blockIdx.x, tid = threadIdx.x;
    for (int g = tid; g < NGROUP; g += 256) { base[g] = pbase[b * NGROUP + g]; cnt[g] = 0; }
    __syncthreads();
    float rsv = rs[0], sg = sigma[0];
    int beg = b * CH_PRE, end = beg + CH_PRE;
    for (int i = beg + tid; i < end; i += 256) {
        float r  = e[i];
        float d  = r - rsv;
        float gauss = expf(-(d * d) / (sg * sg));
        float cut   = 0.5f * cosf(r * (float)(M_PI / (double)RCUT));
        cut = (r < RCUT) ? cut : 0.0f;
        float fe = gauss * cut;
        int dn = dst[i];
        int g  = dn >> 6;
        int lr = atomicAdd(&cnt[g], 1);          // LDS atomic
        metaT[base[g] + lr] = make_int2(src[i] * (DIM * 2) | ((dn & 63) << 24),
                                        __float_as_int(fe));
    }
}

// ---------------- 64-bin counting sort per group -> node-exact CSR ---------
__global__ __launch_bounds__(256) void tagsort_kernel(
        const int2* __restrict__ metaT,
        const int*  __restrict__ goff,
        int2* __restrict__ meta,
        int*  __restrict__ off) {
    __shared__ int cnt[64], base[64], cur[64];
    int g = blockIdx.x, tid = threadIdx.x;
    int sbeg = goff[g], send = goff[g + 1];
    if (tid < 64) cnt[tid] = 0;
    __syncthreads();
    for (int i = sbeg + tid; i < send; i += 256)
        atomicAdd(&cnt[(metaT[i].x >> 24) & 63], 1);   // LDS atomic
    __syncthreads();
    if (tid == 0) {
        int run = 0;
        #pragma unroll
        for (int t = 0; t < 64; ++t) { base[t] = run; cur[t] = run; run += cnt[t]; }
    }
    __syncthreads();
    if (tid < 64) {
        int node = g * 64 + tid;
        if (node <= N_NODES) off[node] = sbeg + base[tid];
    }
    __syncthreads();
    for (int i = sbeg + tid; i < send; i += 256) {
        int2 m = metaT[i];
        int tag = (m.x >> 24) & 63;
        int lr = atomicAdd(&cur[tag], 1);              // LDS atomic
        meta[sbeg + lr] = make_int2(m.x & 0x00FFFFFF, m.y);
    }
}

// ---------------- fused layer: 16 waves = 16 nodes -> one MFMA M-tile -------
// Wave wv gathers node blk*16+wv (round-6 structure, 16-edge unroll, bf16 skip),
// stages its row in LDS; after one barrier waves 0..7 do the 16x128 GEMM tile.
#define EDGE2(mx, mf, rr)                                        \
    do {                                                         \
        float ff = __int_as_float(mf);                           \
        a0 = fmaf(ff, bf_lo(rr), a0);                            \
        a1 = fmaf(ff, bf_hi(rr), a1);                            \
    } while (0)

__global__ __launch_bounds__(1024) void layer_kernel(
        const unsigned short* __restrict__ cur,   // bf16 [N_PAD, DIM]
        const unsigned short* __restrict__ vb,    // bf16 skip [N_PAD, DIM]
        const int2*  __restrict__ meta,
        const int*   __restrict__ off,
        const uint4* __restrict__ wfrag,
        const float* __restrict__ bias,
        unsigned short* __restrict__ out_bf,
        float* __restrict__ out_f,
        int last) {
    __shared__ __align__(16) unsigned short xs[16 * 144];

    int tid  = threadIdx.x;
    int wv   = tid >> 6, lane = tid & 63;
    int n    = blockIdx.x * 16 + wv;

    float a0 = 0.f, a1 = 0.f;
    int beg = 0, end = 0;
    if (n < N_NODES) {
        beg = __builtin_amdgcn_readfirstlane(off[n]);
        end = __builtin_amdgcn_readfirstlane(off[n + 1]);
    }
    const char* base = (const char*)cur + lane * 4;

    int c = beg;
    if ((c & 1) && c < end) {
        int2 m = meta[c];
        unsigned rr = *(const unsigned*)(base + (unsigned)m.x);
        EDGE2(m.x, m.y, rr);
        ++c;
    }
    for (; c + 16 <= end; c += 16) {
        int4 m0 = *(const int4*)(meta + c);
        int4 m1 = *(const int4*)(meta + c + 2);
        int4 m2 = *(const int4*)(meta + c + 4);
        int4 m3 = *(const int4*)(meta + c + 6);
        int4 m4 = *(const int4*)(meta + c + 8);
        int4 m5 = *(const int4*)(meta + c + 10);
        int4 m6 = *(const int4*)(meta + c + 12);
        int4 m7 = *(const int4*)(meta + c + 14);
        unsigned r0  = *(const unsigned*)(base + (unsigned)m0.x);
        unsigned r1  = *(const unsigned*)(base + (unsigned)m0.z);
        unsigned r2  = *(const unsigned*)(base + (unsigned)m1.x);
        unsigned r3  = *(const unsigned*)(base + (unsigned)m1.z);
        unsigned r4  = *(const unsigned*)(base + (unsigned)m2.x);
        unsigned r5  = *(const unsigned*)(base + (unsigned)m2.z);
        unsigned r6  = *(const unsigned*)(base + (unsigned)m3.x);
        unsigned r7  = *(const unsigned*)(base + (unsigned)m3.z);
        unsigned r8  = *(const unsigned*)(base + (unsigned)m4.x);
        unsigned r9  = *(const unsigned*)(base + (unsigned)m4.z);
        unsigned r10 = *(const unsigned*)(base + (unsigned)m5.x);
        unsigned r11 = *(const unsigned*)(base + (unsigned)m5.z);
        unsigned r12 = *(const unsigned*)(base + (unsigned)m6.x);
        unsigned r13 = *(const unsigned*)(base + (unsigned)m6.z);
        unsigned r14 = *(const unsigned*)(base + (unsigned)m7.x);
        unsigned r15 = *(const unsigned*)(base + (unsigned)m7.z);
        EDGE2(m0.x, m0.y, r0);  EDGE2(m0.z, m0.w, r1);
        EDGE2(m1.x, m1.y, r2);  EDGE2(m1.z, m1.w, r3);
        EDGE2(m2.x, m2.y, r4);  EDGE2(m2.z, m2.w, r5);
        EDGE2(m3.x, m3.y, r6);  EDGE2(m3.z, m3.w, r7);
        EDGE2(m4.x, m4.y, r8);  EDGE2(m4.z, m4.w, r9);
        EDGE2(m5.x, m5.y, r10); EDGE2(m5.z, m5.w, r11);
        EDGE2(m6.x, m6.y, r12); EDGE2(m6.z, m6.w, r13);
        EDGE2(m7.x, m7.y, r14); EDGE2(m7.z, m7.w, r15);
    }
    if (c + 8 <= end) {
        int4 m0 = *(const int4*)(meta + c);
        int4 m1 = *(const int4*)(meta + c + 2);
        int4 m2 = *(const int4*)(meta + c + 4);
        int4 m3 = *(const int4*)(meta + c + 6);
        unsigned r0 = *(const unsigned*)(base + (unsigned)m0.x);
        unsigned r1 = *(const unsigned*)(base + (unsigned)m0.z);
        unsigned r2 = *(const unsigned*)(base + (unsigned)m1.x);
        unsigned r3 = *(const unsigned*)(base + (unsigned)m1.z);
        unsigned r4 = *(const unsigned*)(base + (unsigned)m2.x);
        unsigned r5 = *(const unsigned*)(base + (unsigned)m2.z);
        unsigned r6 = *(const unsigned*)(base + (unsigned)m3.x);
        unsigned r7 = *(const unsigned*)(base + (unsigned)m3.z);
        EDGE2(m0.x, m0.y, r0); EDGE2(m0.z, m0.w, r1);
        EDGE2(m1.x, m1.y, r2); EDGE2(m1.z, m1.w, r3);
        EDGE2(m2.x, m2.y, r4); EDGE2(m2.z, m2.w, r5);
        EDGE2(m3.x, m3.y, r6); EDGE2(m3.z, m3.w, r7);
        c += 8;
    }
    for (; c < end; ++c) {
        int2 m = meta[c];
        unsigned rr = *(const unsigned*)(base + (unsigned)m.x);
        EDGE2(m.x, m.y, rr);
    }

    // skip connection (bf16 v) + stage row in LDS
    if (n < N_NODES) {
        unsigned rr = *(const unsigned*)((const char*)vb + (size_t)n * (DIM * 2) + lane * 4);
        a0 += bf_lo(rr); a1 += bf_hi(rr);
    }
    *(unsigned*)&xs[wv * 144 + lane * 2] =
        (unsigned)f2bf(a0) | ((unsigned)f2bf(a1) << 16);
    __syncthreads();

    // GEMM: waves 0..7 each own col-tile wv (16 cols), 4 MFMAs over K
    if (wv < 8) {
        int quad = lane >> 4, l16 = lane & 15;
        f32x4 acc = {0.f, 0.f, 0.f, 0.f};
        #pragma unroll
        for (int kk = 0; kk < 4; ++kk) {
            bf16x8 af = *(const bf16x8*)&xs[l16 * 144 + kk * 32 + quad * 8];
            uint4 w = wfrag[(kk * 8 + wv) * 64 + lane];
            acc = __builtin_amdgcn_mfma_f32_16x16x32_bf16(af, __builtin_bit_cast(bf16x8, w), acc, 0, 0, 0);
        }
        int rbase = blockIdx.x * 16 + quad * 4;
        int col = wv * 16 + l16;
        float b = bias[col];
        #pragma unroll
        for (int r = 0; r < 4; ++r) {
            int orow = rbase + r;
            if (orow < N_NODES) {
                float val = fmaxf(acc[r] + b, 0.f);
                if (last) out_f[(size_t)orow * DIM + col] = val;
                else      out_bf[(size_t)orow * DIM + col] = f2bf(val);
            }
        }
    }
}

// ---------------------------------------------------------------------------
extern "C" void kernel_launch(void* const* d_in, const int* in_sizes, int n_in,
                              void* d_out, int out_size, void* d_ws, size_t ws_size,
                              hipStream_t stream) {
    const float* v     = (const float*)d_in[0];
    const float* e     = (const float*)d_in[1];
    const int*   src   = (const int*)  d_in[2];
    const int*   dst   = (const int*)  d_in[3];
    const float* Aw    = (const float*)d_in[4];
    const float* Ab    = (const float*)d_in[5];
    const float* rs    = (const float*)d_in[6];
    const float* sigma = (const float*)d_in[7];
    float* out = (float*)d_out;

    // ---- workspace layout (~51.5 MB) ----
    char* p = (char*)d_ws;
    int2*           meta  = (int2*)p;            p += (size_t)N_EDGES * 8;       // 12.8 MB (final CSR)
    unsigned short* bufV  = (unsigned short*)p;  p += (size_t)N_PAD * DIM * 2;   // 12.81 MB
    unsigned short* bufA  = (unsigned short*)p;  p += (size_t)N_PAD * DIM * 2;   // 12.81 MB
    unsigned short* bufB  = (unsigned short*)p;  p += (size_t)N_PAD * DIM * 2;   // 12.81 MB
    uint4*          wfrag = (uint4*)p;           p += 2048 * 16;                 //  32 KB
    int*            off   = (int*)p;             p += (size_t)(N_NODES + 1) * 4;
    int*            gtot  = (int*)p;             p += (NGROUP + 2) * 4;
    int*            goff  = (int*)p;             p += (NGROUP + 2) * 4;
    // aliases (dead before host buffer's first write):
    int2* metaT   = (int2*)bufA;                 // unsorted meta, dead after tagsort
    int*  partial = (int*)bufB;                  // NB_PRE*NGROUP*4 = 400 KB
    int*  pbase   = partial + NB_PRE * NGROUP;   // 400 KB, dead after reorder

    prep_kernel<<<6258, 256, 0, stream>>>(v, bufV, Aw, wfrag);
    countp_kernel<<<NB_PRE, 256, 0, stream>>>(dst, partial);
    ktot_kernel<<<(NGROUP + 255) / 256, 256, 0, stream>>>(partial, gtot);
    kscan_kernel<<<1, 256, 0, stream>>>(gtot, goff);
    kbase_kernel<<<(NGROUP + 255) / 256, 256, 0, stream>>>(partial, goff, pbase);
    reorder_kernel<<<NB_PRE, 256, 0, stream>>>(e, src, dst, rs, sigma, pbase, metaT);
    tagsort_kernel<<<NGROUP, 256, 0, stream>>>(metaT, goff, meta, off);

    const int LB = N_PAD / 16;   // 3128 blocks, 16 waves = 16 nodes each
    // L0: bufV -> bufA ; L1: bufA -> bufB ; L2: bufB -> out (fp32)
    layer_kernel<<<LB, 1024, 0, stream>>>(bufV, bufV, meta, off, wfrag, Ab, bufA, nullptr, 0);
    layer_kernel<<<LB, 1024, 0, stream>>>(bufA, bufV, meta, off, wfrag, Ab, bufB, nullptr, 0);
    layer_kernel<<<LB, 1024, 0, stream>>>(bufB, bufV, meta, off, wfrag, Ab, nullptr, out, 1);
}

// Round 9
// 362.792 us; speedup vs baseline: 1.1669x; 1.1669x over previous
//
#include <hip/hip_runtime.h>
#include <math.h>

#define N_NODES 50000
#define N_PAD   50048              // rows padded to multiple of 64
#define N_EDGES 1600000
#define DIM     128
#define RCUT    5.0f
#define NGROUP  (N_PAD / 64)       // 782 groups of 64 nodes
#define NB_PRE  256
#define CH_PRE  (N_EDGES / NB_PRE) // 6250 edges per preprocessing block
#define NB_CONV 6250               // convert blocks in preA
#define NB_WPREP 8                 // wprep blocks in preA

typedef __attribute__((ext_vector_type(8))) __bf16 bf16x8;
typedef __attribute__((ext_vector_type(4))) float  f32x4;

// ---------------- bf16 helpers ----------------
__device__ __forceinline__ float bf_lo(unsigned int u) { return __uint_as_float(u << 16); }
__device__ __forceinline__ float bf_hi(unsigned int u) { return __uint_as_float(u & 0xffff0000u); }
__device__ __forceinline__ unsigned short f2bf(float x) {
    unsigned int u = __float_as_uint(x);
    u += 0x7fffu + ((u >> 16) & 1u);   // round-to-nearest-even
    return (unsigned short)(u >> 16);
}

// ---------------- preA: convert v->bf16  |  W->frags  |  group-64 histogram ---
__global__ __launch_bounds__(256) void preA_kernel(
        const float* __restrict__ v, unsigned short* __restrict__ vb,
        const float* __restrict__ Aw, uint4* __restrict__ wfrag,
        const int* __restrict__ dst, int* __restrict__ partial) {
    int b = blockIdx.x;
    if (b < NB_CONV) {
        int i = b * 256 + threadIdx.x;           // exactly N_NODES*DIM/4
        float4 x = ((const float4*)v)[i];
        uint2 o;
        o.x = (unsigned)f2bf(x.x) | ((unsigned)f2bf(x.y) << 16);
        o.y = (unsigned)f2bf(x.z) | ((unsigned)f2bf(x.w) << 16);
        ((uint2*)vb)[i] = o;
    } else if (b < NB_CONV + NB_WPREP) {
        int t = (b - NB_CONV) * 256 + threadIdx.x;   // 0..2047
        int lane = t & 63, nt = (t >> 6) & 7, kk = t >> 9;
        int n  = nt * 16 + (lane & 15);
        int k0 = kk * 32 + (lane >> 4) * 8;
        unsigned short h[8];
        #pragma unroll
        for (int i = 0; i < 8; ++i) h[i] = f2bf(Aw[n * DIM + k0 + i]);
        uint4 o;
        o.x = h[0] | ((unsigned)h[1] << 16); o.y = h[2] | ((unsigned)h[3] << 16);
        o.z = h[4] | ((unsigned)h[5] << 16); o.w = h[6] | ((unsigned)h[7] << 16);
        wfrag[t] = o;
    } else {
        __shared__ int h[NGROUP];                // 3.1 KB
        int cb = b - NB_CONV - NB_WPREP, tid = threadIdx.x;
        for (int g = tid; g < NGROUP; g += 256) h[g] = 0;
        __syncthreads();
        int beg = cb * CH_PRE, end = beg + CH_PRE;
        for (int i = beg + tid; i < end; i += 256)
            atomicAdd(&h[dst[i] >> 6], 1);       // LDS atomic
        __syncthreads();
        for (int g = tid; g < NGROUP; g += 256) partial[cb * NGROUP + g] = h[g];
    }
}

// ---------------- preB: group totals + scan + per-(block,group) bases -------
__global__ __launch_bounds__(1024) void preB_kernel(
        const int* __restrict__ partial,
        int* __restrict__ goff,
        int* __restrict__ pbase) {
    __shared__ int part[1024];
    int tid = threadIdx.x;
    int s = 0;
    if (tid < NGROUP)
        for (int b = 0; b < NB_PRE; ++b) s += partial[b * NGROUP + tid];
    part[tid] = (tid < NGROUP) ? s : 0;
    __syncthreads();
    for (int d = 1; d < 1024; d <<= 1) {
        int val = (tid >= d) ? part[tid - d] : 0;
        __syncthreads(); part[tid] += val; __syncthreads();
    }
    int base = (tid == 0) ? 0 : part[tid - 1];
    if (tid < NGROUP) {
        goff[tid] = base;
        int run = base;
        for (int b = 0; b < NB_PRE; ++b) {
            pbase[b * NGROUP + tid] = run;
            run += partial[b * NGROUP + tid];
        }
    }
    if (tid == 0) goff[NGROUP] = N_EDGES;
}

// ---------------- reorder into group-64 CSR with 6-bit node tags ----------
// metaT[slot] = { src*256 | (dst&63)<<24, bitcast(f) }
__global__ __launch_bounds__(256) void reorder_kernel(
        const float* __restrict__ e,
        const int*   __restrict__ src,
        const int*   __restrict__ dst,
        const float* __restrict__ rs,
        const float* __restrict__ sigma,
        const int*   __restrict__ pbase,
        int2* __restrict__ metaT) {
    __shared__ int base[NGROUP];
    __shared__ int cnt[NGROUP];
    int b = blockIdx.x, tid = threadIdx.x;
    for (int g = tid; g < NGROUP; g += 256) { base[g] = pbase[b * NGROUP + g]; cnt[g] = 0; }
    __syncthreads();
    float rsv = rs[0], sg = sigma[0];
    int beg = b * CH_PRE, end = beg + CH_PRE;
    for (int i = beg + tid; i < end; i += 256) {
        float r  = e[i];
        float d  = r - rsv;
        float gauss = expf(-(d * d) / (sg * sg));
        float cut   = 0.5f * cosf(r * (float)(M_PI / (double)RCUT));
        cut = (r < RCUT) ? cut : 0.0f;
        float fe = gauss * cut;
        int dn = dst[i];
        int g  = dn >> 6;
        int lr = atomicAdd(&cnt[g], 1);          // LDS atomic
        metaT[base[g] + lr] = make_int2(src[i] * (DIM * 2) | ((dn & 63) << 24),
                                        __float_as_int(fe));
    }
}

// ---------------- 64-bin counting sort per group -> node-exact CSR ---------
__global__ __launch_bounds__(256) void tagsort_kernel(
        const int2* __restrict__ metaT,
        const int*  __restrict__ goff,
        int2* __restrict__ meta,
        int*  __restrict__ off) {
    __shared__ int cnt[64], base[64], cur[64];
    int g = blockIdx.x, tid = threadIdx.x;
    int sbeg = goff[g], send = goff[g + 1];
    if (tid < 64) cnt[tid] = 0;
    __syncthreads();
    for (int i = sbeg + tid; i < send; i += 256)
        atomicAdd(&cnt[(metaT[i].x >> 24) & 63], 1);   // LDS atomic
    __syncthreads();
    if (tid == 0) {
        int run = 0;
        #pragma unroll
        for (int t = 0; t < 64; ++t) { base[t] = run; cur[t] = run; run += cnt[t]; }
    }
    __syncthreads();
    if (tid < 64) {
        int node = g * 64 + tid;
        if (node <= N_NODES) off[node] = sbeg + base[tid];
    }
    __syncthreads();
    for (int i = sbeg + tid; i < send; i += 256) {
        int2 m = metaT[i];
        int tag = (m.x >> 24) & 63;
        int lr = atomicAdd(&cur[tag], 1);              // LDS atomic
        meta[sbeg + lr] = make_int2(m.x & 0x00FFFFFF, m.y);
    }
}

// ---------------- gather: one wave per node, lane owns 2 dims ----------------
// svf[n] = v[n] + sum_e f[e] * cur[src[e]]   (bf16 out), 16-edge unroll
#define EDGE2(mx, mf, rr)                                        \
    do {                                                         \
        float ff = __int_as_float(mf);                           \
        a0 = fmaf(ff, bf_lo(rr), a0);                            \
        a1 = fmaf(ff, bf_hi(rr), a1);                            \
    } while (0)

__global__ __launch_bounds__(256) void gather_kernel(
        const unsigned short* __restrict__ cur,   // bf16 [N_PAD, DIM]
        const float* __restrict__ v,              // fp32 [N, DIM]
        const int2*  __restrict__ meta,
        const int*   __restrict__ off,
        unsigned short* __restrict__ svf) {       // bf16 [N_PAD, DIM]
    int n    = (blockIdx.x << 2) + (threadIdx.x >> 6);   // 12500 blocks -> n < 50000
    int lane = threadIdx.x & 63;

    float2 vv = *(const float2*)(v + (size_t)n * DIM + lane * 2);
    float a0 = vv.x, a1 = vv.y;

    int beg = __builtin_amdgcn_readfirstlane(off[n]);
    int end = __builtin_amdgcn_readfirstlane(off[n + 1]);
    const char* base = (const char*)cur + lane * 4;

    int c = beg;
    if ((c & 1) && c < end) {
        int2 m = meta[c];
        unsigned rr = *(const unsigned*)(base + (unsigned)m.x);
        EDGE2(m.x, m.y, rr);
        ++c;
    }
    for (; c + 16 <= end; c += 16) {
        int4 m0 = *(const int4*)(meta + c);
        int4 m1 = *(const int4*)(meta + c + 2);
        int4 m2 = *(const int4*)(meta + c + 4);
        int4 m3 = *(const int4*)(meta + c + 6);
        int4 m4 = *(const int4*)(meta + c + 8);
        int4 m5 = *(const int4*)(meta + c + 10);
        int4 m6 = *(const int4*)(meta + c + 12);
        int4 m7 = *(const int4*)(meta + c + 14);
        unsigned r0  = *(const unsigned*)(base + (unsigned)m0.x);
        unsigned r1  = *(const unsigned*)(base + (unsigned)m0.z);
        unsigned r2  = *(const unsigned*)(base + (unsigned)m1.x);
        unsigned r3  = *(const unsigned*)(base + (unsigned)m1.z);
        unsigned r4  = *(const unsigned*)(base + (unsigned)m2.x);
        unsigned r5  = *(const unsigned*)(base + (unsigned)m2.z);
        unsigned r6  = *(const unsigned*)(base + (unsigned)m3.x);
        unsigned r7  = *(const unsigned*)(base + (unsigned)m3.z);
        unsigned r8  = *(const unsigned*)(base + (unsigned)m4.x);
        unsigned r9  = *(const unsigned*)(base + (unsigned)m4.z);
        unsigned r10 = *(const unsigned*)(base + (unsigned)m5.x);
        unsigned r11 = *(const unsigned*)(base + (unsigned)m5.z);
        unsigned r12 = *(const unsigned*)(base + (unsigned)m6.x);
        unsigned r13 = *(const unsigned*)(base + (unsigned)m6.z);
        unsigned r14 = *(const unsigned*)(base + (unsigned)m7.x);
        unsigned r15 = *(const unsigned*)(base + (unsigned)m7.z);
        EDGE2(m0.x, m0.y, r0);  EDGE2(m0.z, m0.w, r1);
        EDGE2(m1.x, m1.y, r2);  EDGE2(m1.z, m1.w, r3);
        EDGE2(m2.x, m2.y, r4);  EDGE2(m2.z, m2.w, r5);
        EDGE2(m3.x, m3.y, r6);  EDGE2(m3.z, m3.w, r7);
        EDGE2(m4.x, m4.y, r8);  EDGE2(m4.z, m4.w, r9);
        EDGE2(m5.x, m5.y, r10); EDGE2(m5.z, m5.w, r11);
        EDGE2(m6.x, m6.y, r12); EDGE2(m6.z, m6.w, r13);
        EDGE2(m7.x, m7.y, r14); EDGE2(m7.z, m7.w, r15);
    }
    if (c + 8 <= end) {
        int4 m0 = *(const int4*)(meta + c);
        int4 m1 = *(const int4*)(meta + c + 2);
        int4 m2 = *(const int4*)(meta + c + 4);
        int4 m3 = *(const int4*)(meta + c + 6);
        unsigned r0 = *(const unsigned*)(base + (unsigned)m0.x);
        unsigned r1 = *(const unsigned*)(base + (unsigned)m0.z);
        unsigned r2 = *(const unsigned*)(base + (unsigned)m1.x);
        unsigned r3 = *(const unsigned*)(base + (unsigned)m1.z);
        unsigned r4 = *(const unsigned*)(base + (unsigned)m2.x);
        unsigned r5 = *(const unsigned*)(base + (unsigned)m2.z);
        unsigned r6 = *(const unsigned*)(base + (unsigned)m3.x);
        unsigned r7 = *(const unsigned*)(base + (unsigned)m3.z);
        EDGE2(m0.x, m0.y, r0); EDGE2(m0.z, m0.w, r1);
        EDGE2(m1.x, m1.y, r2); EDGE2(m1.z, m1.w, r3);
        EDGE2(m2.x, m2.y, r4); EDGE2(m2.z, m2.w, r5);
        EDGE2(m3.x, m3.y, r6); EDGE2(m3.z, m3.w, r7);
        c += 8;
    }
    for (; c < end; ++c) {
        int2 m = meta[c];
        unsigned rr = *(const unsigned*)(base + (unsigned)m.x);
        EDGE2(m.x, m.y, rr);
    }
    unsigned o = (unsigned)f2bf(a0) | ((unsigned)f2bf(a1) << 16);
    *(unsigned*)(svf + (size_t)n * DIM + lane * 2) = o;
}

// ---------------- GEMM+bias+ReLU via MFMA ----------------
__global__ __launch_bounds__(256) void gemm_kernel(
        const unsigned short* __restrict__ X,     // bf16 [N_PAD, DIM]
        const uint4* __restrict__ wfrag,          // [4][8][64] fragments
        const float* __restrict__ bias,
        unsigned short* __restrict__ out_bf,
        float* __restrict__ out_f,
        int last) {
    __shared__ uint4 wlds[2048];                  // 32 KB
    int tid = threadIdx.x;
    for (int i = tid; i < 2048; i += 256) wlds[i] = wfrag[i];

    int wv = tid >> 6, lane = tid & 63;
    int quad = lane >> 4, l16 = lane & 15;
    int row = blockIdx.x * 64 + wv * 16 + l16;

    f32x4 acc[8];
    #pragma unroll
    for (int i = 0; i < 8; ++i) acc[i] = (f32x4){0.f, 0.f, 0.f, 0.f};

    __syncthreads();

    const unsigned short* xp = X + (size_t)row * DIM + quad * 8;
    #pragma unroll
    for (int kk = 0; kk < 4; ++kk) {
        bf16x8 af = *(const bf16x8*)(xp + kk * 32);
        #pragma unroll
        for (int nt = 0; nt < 8; ++nt) {
            uint4 w = wlds[(kk * 8 + nt) * 64 + lane];
            bf16x8 bfr = __builtin_bit_cast(bf16x8, w);
            acc[nt] = __builtin_amdgcn_mfma_f32_16x16x32_bf16(af, bfr, acc[nt], 0, 0, 0);
        }
    }

    int orow0 = blockIdx.x * 64 + wv * 16 + quad * 4;
    #pragma unroll
    for (int nt = 0; nt < 8; ++nt) {
        int col = nt * 16 + l16;
        float b = bias[col];
        #pragma unroll
        for (int r = 0; r < 4; ++r) {
            int orow = orow0 + r;
            if (orow < N_NODES) {
                float val = fmaxf(acc[nt][r] + b, 0.f);
                if (last) out_f[(size_t)orow * DIM + col] = val;
                else      out_bf[(size_t)orow * DIM + col] = f2bf(val);
            }
        }
    }
}

// ---------------------------------------------------------------------------
extern "C" void kernel_launch(void* const* d_in, const int* in_sizes, int n_in,
                              void* d_out, int out_size, void* d_ws, size_t ws_size,
                              hipStream_t stream) {
    const float* v     = (const float*)d_in[0];
    const float* e     = (const float*)d_in[1];
    const int*   src   = (const int*)  d_in[2];
    const int*   dst   = (const int*)  d_in[3];
    const float* Aw    = (const float*)d_in[4];
    const float* Ab    = (const float*)d_in[5];
    const float* rs    = (const float*)d_in[6];
    const float* sigma = (const float*)d_in[7];
    float* out = (float*)d_out;

    // ---- workspace layout (~51.5 MB) ----
    char* p = (char*)d_ws;
    int2*           meta  = (int2*)p;            p += (size_t)N_EDGES * 8;       // 12.8 MB (final CSR)
    unsigned short* bufV  = (unsigned short*)p;  p += (size_t)N_PAD * DIM * 2;   // 12.81 MB
    unsigned short* bufA  = (unsigned short*)p;  p += (size_t)N_PAD * DIM * 2;   // 12.81 MB
    unsigned short* bufB  = (unsigned short*)p;  p += (size_t)N_PAD * DIM * 2;   // 12.81 MB
    uint4*          wfrag = (uint4*)p;           p += 2048 * 16;                 //  32 KB
    int*            off   = (int*)p;             p += (size_t)(N_NODES + 1) * 4;
    int*            goff  = (int*)p;             p += (NGROUP + 2) * 4;
    // aliases (dead before host buffer's first write):
    int2* metaT   = (int2*)bufA;                 // unsorted meta, dead after tagsort
    int*  partial = (int*)bufB;                  // NB_PRE*NGROUP*4 = 800 KB
    int*  pbase   = partial + NB_PRE * NGROUP;   // 800 KB, dead after reorder

    preA_kernel<<<NB_CONV + NB_WPREP + NB_PRE, 256, 0, stream>>>(
        v, bufV, Aw, wfrag, dst, partial);
    preB_kernel<<<1, 1024, 0, stream>>>(partial, goff, pbase);
    reorder_kernel<<<NB_PRE, 256, 0, stream>>>(e, src, dst, rs, sigma, pbase, metaT);
    tagsort_kernel<<<NGROUP, 256, 0, stream>>>(metaT, goff, meta, off);

    const int GB = N_NODES / 4;   // 12500 blocks, 4 waves each, no barrier
    const int MB = N_PAD / 64;    // 782 blocks

    // L0: bufV -> bufA -> bufB ; L1: bufB -> bufA -> bufV ; L2: bufV -> bufA -> out
    gather_kernel<<<GB, 256, 0, stream>>>(bufV, v, meta, off, bufA);
    gemm_kernel<<<MB, 256, 0, stream>>>(bufA, wfrag, Ab, bufB, nullptr, 0);
    gather_kernel<<<GB, 256, 0, stream>>>(bufB, v, meta, off, bufA);
    gemm_kernel<<<MB, 256, 0, stream>>>(bufA, wfrag, Ab, bufV, nullptr, 0);
    gather_kernel<<<GB, 256, 0, stream>>>(bufV, v, meta, off, bufA);
    gemm_kernel<<<MB, 256, 0, stream>>>(bufA, wfrag, Ab, nullptr, out, 1);
}

// Round 11
// 355.746 us; speedup vs baseline: 1.1900x; 1.0198x over previous
//
#include <hip/hip_runtime.h>
#include <math.h>

#define N_NODES 50000
#define N_PAD   50048              // rows padded to multiple of 64
#define N_EDGES 1600000
#define DIM     128
#define RCUT    5.0f
#define NGROUP  (N_PAD / 64)       // 782 groups of 64 nodes
#define NB_PRE  512
#define CH_PRE  (N_EDGES / NB_PRE) // 3125 edges per preprocessing block
#define NB_CONV 6250               // convert blocks in preA
#define NB_WPREP 8                 // wprep blocks in preA

typedef __attribute__((ext_vector_type(8))) __bf16 bf16x8;
typedef __attribute__((ext_vector_type(4))) float  f32x4;

// ---------------- bf16 helpers ----------------
__device__ __forceinline__ float bf_lo(unsigned int u) { return __uint_as_float(u << 16); }
__device__ __forceinline__ float bf_hi(unsigned int u) { return __uint_as_float(u & 0xffff0000u); }
__device__ __forceinline__ unsigned short f2bf(float x) {
    unsigned int u = __float_as_uint(x);
    u += 0x7fffu + ((u >> 16) & 1u);   // round-to-nearest-even
    return (unsigned short)(u >> 16);
}

// ---------------- preA: convert v->bf16  |  W->frags  |  group-64 histogram ---
__global__ __launch_bounds__(256) void preA_kernel(
        const float* __restrict__ v, unsigned short* __restrict__ vb,
        const float* __restrict__ Aw, uint4* __restrict__ wfrag,
        const int* __restrict__ dst, int* __restrict__ partial) {
    int b = blockIdx.x;
    if (b < NB_CONV) {
        int i = b * 256 + threadIdx.x;           // exactly N_NODES*DIM/4
        float4 x = ((const float4*)v)[i];
        uint2 o;
        o.x = (unsigned)f2bf(x.x) | ((unsigned)f2bf(x.y) << 16);
        o.y = (unsigned)f2bf(x.z) | ((unsigned)f2bf(x.w) << 16);
        ((uint2*)vb)[i] = o;
    } else if (b < NB_CONV + NB_WPREP) {
        int t = (b - NB_CONV) * 256 + threadIdx.x;   // 0..2047
        int lane = t & 63, nt = (t >> 6) & 7, kk = t >> 9;
        int n  = nt * 16 + (lane & 15);
        int k0 = kk * 32 + (lane >> 4) * 8;
        unsigned short h[8];
        #pragma unroll
        for (int i = 0; i < 8; ++i) h[i] = f2bf(Aw[n * DIM + k0 + i]);
        uint4 o;
        o.x = h[0] | ((unsigned)h[1] << 16); o.y = h[2] | ((unsigned)h[3] << 16);
        o.z = h[4] | ((unsigned)h[5] << 16); o.w = h[6] | ((unsigned)h[7] << 16);
        wfrag[t] = o;
    } else {
        __shared__ int h[NGROUP];                // 3.1 KB
        int cb = b - NB_CONV - NB_WPREP, tid = threadIdx.x;
        for (int g = tid; g < NGROUP; g += 256) h[g] = 0;
        __syncthreads();
        int beg = cb * CH_PRE, end = beg + CH_PRE;
        for (int i = beg + tid; i < end; i += 256)
            atomicAdd(&h[dst[i] >> 6], 1);       // LDS atomic
        __syncthreads();
        for (int g = tid; g < NGROUP; g += 256) partial[cb * NGROUP + g] = h[g];
    }
}

// ---------------- group totals (coalesced over g, 4 blocks) ----------------
__global__ __launch_bounds__(256) void ktot_kernel(const int* __restrict__ partial,
                                                   int* __restrict__ gtot) {
    int g = blockIdx.x * 256 + threadIdx.x;
    if (g >= NGROUP) return;
    int s = 0;
    for (int b = 0; b < NB_PRE; ++b) s += partial[b * NGROUP + g];
    gtot[g] = s;
}

// ---------------- exclusive scan over 782 group totals ----------------
__global__ __launch_bounds__(256) void kscan_kernel(const int* __restrict__ gtot,
                                                    int* __restrict__ goff) {
    __shared__ int part[256];
    int tid = threadIdx.x;
    int i0 = tid * 4;
    int v[4]; int s = 0;
    #pragma unroll
    for (int k = 0; k < 4; ++k) { int i = i0 + k; v[k] = (i < NGROUP) ? gtot[i] : 0; s += v[k]; }
    part[tid] = s; __syncthreads();
    for (int d = 1; d < 256; d <<= 1) {
        int val = (tid >= d) ? part[tid - d] : 0;
        __syncthreads(); part[tid] += val; __syncthreads();
    }
    int run = (tid == 0) ? 0 : part[tid - 1];
    #pragma unroll
    for (int k = 0; k < 4; ++k) {
        int i = i0 + k;
        if (i < NGROUP) { goff[i] = run; run += v[k]; }
    }
    if (tid == 0) goff[NGROUP] = N_EDGES;
}

// ---------------- per-(block,group) bases (coalesced over g, 4 blocks) ------
__global__ __launch_bounds__(256) void kbase_kernel(const int* __restrict__ partial,
                                                    const int* __restrict__ goff,
                                                    int* __restrict__ pbase) {
    int g = blockIdx.x * 256 + threadIdx.x;
    if (g >= NGROUP) return;
    int run = goff[g];
    for (int b = 0; b < NB_PRE; ++b) {
        pbase[b * NGROUP + g] = run;
        run += partial[b * NGROUP + g];
    }
}

// ---------------- reorder into group-64 CSR with 6-bit node tags ----------
// 512 threads/block for occupancy. metaT[slot] = { src*256|(dst&63)<<24, f }
__global__ __launch_bounds__(512) void reorder_kernel(
        const float* __restrict__ e,
        const int*   __restrict__ src,
        const int*   __restrict__ dst,
        const float* __restrict__ rs,
        const float* __restrict__ sigma,
        const int*   __restrict__ pbase,
        int2* __restrict__ metaT) {
    __shared__ int base[NGROUP];
    __shared__ int cnt[NGROUP];
    int b = blockIdx.x, tid = threadIdx.x;
    for (int g = tid; g < NGROUP; g += 512) { base[g] = pbase[b * NGROUP + g]; cnt[g] = 0; }
    __syncthreads();
    float rsv = rs[0], sg = sigma[0];
    int beg = b * CH_PRE, end = beg + CH_PRE;
    for (int i = beg + tid; i < end; i += 512) {
        float r  = e[i];
        float d  = r - rsv;
        float gauss = expf(-(d * d) / (sg * sg));
        float cut   = 0.5f * cosf(r * (float)(M_PI / (double)RCUT));
        cut = (r < RCUT) ? cut : 0.0f;
        float fe = gauss * cut;
        int dn = dst[i];
        int g  = dn >> 6;
        int lr = atomicAdd(&cnt[g], 1);          // LDS atomic
        metaT[base[g] + lr] = make_int2(src[i] * (DIM * 2) | ((dn & 63) << 24),
                                        __float_as_int(fe));
    }
}

// ---------------- 64-bin counting sort per group -> node-exact CSR ---------
__global__ __launch_bounds__(256) void tagsort_kernel(
        const int2* __restrict__ metaT,
        const int*  __restrict__ goff,
        int2* __restrict__ meta,
        int*  __restrict__ off) {
    __shared__ int cnt[64], base[64], cur[64];
    int g = blockIdx.x, tid = threadIdx.x;
    int sbeg = goff[g], send = goff[g + 1];
    if (tid < 64) cnt[tid] = 0;
    __syncthreads();
    for (int i = sbeg + tid; i < send; i += 256)
        atomicAdd(&cnt[(metaT[i].x >> 24) & 63], 1);   // LDS atomic
    __syncthreads();
    if (tid == 0) {
        int run = 0;
        #pragma unroll
        for (int t = 0; t < 64; ++t) { base[t] = run; cur[t] = run; run += cnt[t]; }
    }
    __syncthreads();
    if (tid < 64) {
        int node = g * 64 + tid;
        if (node <= N_NODES) off[node] = sbeg + base[tid];
    }
    __syncthreads();
    for (int i = sbeg + tid; i < send; i += 256) {
        int2 m = metaT[i];
        int tag = (m.x >> 24) & 63;
        int lr = atomicAdd(&cur[tag], 1);              // LDS atomic
        meta[sbeg + lr] = make_int2(m.x & 0x00FFFFFF, m.y);
    }
}

// ---------------- gather: one wave per node, lane owns 2 dims ----------------
// svf[n] = vb[n] + sum_e f[e] * cur[src[e]]   (bf16 in/out), 16-edge unroll
#define EDGE2(mx, mf, rr)                                        \
    do {                                                         \
        float ff = __int_as_float(mf);                           \
        a0 = fmaf(ff, bf_lo(rr), a0);                            \
        a1 = fmaf(ff, bf_hi(rr), a1);                            \
    } while (0)

__global__ __launch_bounds__(256) void gather_kernel(
        const unsigned short* __restrict__ cur,   // bf16 [N_PAD, DIM]
        const unsigned short* __restrict__ vb,    // bf16 skip [N_PAD, DIM] (NEVER overwritten)
        const int2*  __restrict__ meta,
        const int*   __restrict__ off,
        unsigned short* __restrict__ svf) {       // bf16 [N_PAD, DIM]
    int n    = (blockIdx.x << 2) + (threadIdx.x >> 6);   // 12500 blocks -> n < 50000
    int lane = threadIdx.x & 63;

    unsigned vv = *(const unsigned*)((const char*)vb + (size_t)n * (DIM * 2) + lane * 4);
    float a0 = bf_lo(vv), a1 = bf_hi(vv);

    int beg = __builtin_amdgcn_readfirstlane(off[n]);
    int end = __builtin_amdgcn_readfirstlane(off[n + 1]);
    const char* base = (const char*)cur + lane * 4;

    int c = beg;
    if ((c & 1) && c < end) {
        int2 m = meta[c];
        unsigned rr = *(const unsigned*)(base + (unsigned)m.x);
        EDGE2(m.x, m.y, rr);
        ++c;
    }
    for (; c + 16 <= end; c += 16) {
        int4 m0 = *(const int4*)(meta + c);
        int4 m1 = *(const int4*)(meta + c + 2);
        int4 m2 = *(const int4*)(meta + c + 4);
        int4 m3 = *(const int4*)(meta + c + 6);
        int4 m4 = *(const int4*)(meta + c + 8);
        int4 m5 = *(const int4*)(meta + c + 10);
        int4 m6 = *(const int4*)(meta + c + 12);
        int4 m7 = *(const int4*)(meta + c + 14);
        unsigned r0  = *(const unsigned*)(base + (unsigned)m0.x);
        unsigned r1  = *(const unsigned*)(base + (unsigned)m0.z);
        unsigned r2  = *(const unsigned*)(base + (unsigned)m1.x);
        unsigned r3  = *(const unsigned*)(base + (unsigned)m1.z);
        unsigned r4  = *(const unsigned*)(base + (unsigned)m2.x);
        unsigned r5  = *(const unsigned*)(base + (unsigned)m2.z);
        unsigned r6  = *(const unsigned*)(base + (unsigned)m3.x);
        unsigned r7  = *(const unsigned*)(base + (unsigned)m3.z);
        unsigned r8  = *(const unsigned*)(base + (unsigned)m4.x);
        unsigned r9  = *(const unsigned*)(base + (unsigned)m4.z);
        unsigned r10 = *(const unsigned*)(base + (unsigned)m5.x);
        unsigned r11 = *(const unsigned*)(base + (unsigned)m5.z);
        unsigned r12 = *(const unsigned*)(base + (unsigned)m6.x);
        unsigned r13 = *(const unsigned*)(base + (unsigned)m6.z);
        unsigned r14 = *(const unsigned*)(base + (unsigned)m7.x);
        unsigned r15 = *(const unsigned*)(base + (unsigned)m7.z);
        EDGE2(m0.x, m0.y, r0);  EDGE2(m0.z, m0.w, r1);
        EDGE2(m1.x, m1.y, r2);  EDGE2(m1.z, m1.w, r3);
        EDGE2(m2.x, m2.y, r4);  EDGE2(m2.z, m2.w, r5);
        EDGE2(m3.x, m3.y, r6);  EDGE2(m3.z, m3.w, r7);
        EDGE2(m4.x, m4.y, r8);  EDGE2(m4.z, m4.w, r9);
        EDGE2(m5.x, m5.y, r10); EDGE2(m5.z, m5.w, r11);
        EDGE2(m6.x, m6.y, r12); EDGE2(m6.z, m6.w, r13);
        EDGE2(m7.x, m7.y, r14); EDGE2(m7.z, m7.w, r15);
    }
    if (c + 8 <= end) {
        int4 m0 = *(const int4*)(meta + c);
        int4 m1 = *(const int4*)(meta + c + 2);
        int4 m2 = *(const int4*)(meta + c + 4);
        int4 m3 = *(const int4*)(meta + c + 6);
        unsigned r0 = *(const unsigned*)(base + (unsigned)m0.x);
        unsigned r1 = *(const unsigned*)(base + (unsigned)m0.z);
        unsigned r2 = *(const unsigned*)(base + (unsigned)m1.x);
        unsigned r3 = *(const unsigned*)(base + (unsigned)m1.z);
        unsigned r4 = *(const unsigned*)(base + (unsigned)m2.x);
        unsigned r5 = *(const unsigned*)(base + (unsigned)m2.z);
        unsigned r6 = *(const unsigned*)(base + (unsigned)m3.x);
        unsigned r7 = *(const unsigned*)(base + (unsigned)m3.z);
        EDGE2(m0.x, m0.y, r0); EDGE2(m0.z, m0.w, r1);
        EDGE2(m1.x, m1.y, r2); EDGE2(m1.z, m1.w, r3);
        EDGE2(m2.x, m2.y, r4); EDGE2(m2.z, m2.w, r5);
        EDGE2(m3.x, m3.y, r6); EDGE2(m3.z, m3.w, r7);
        c += 8;
    }
    for (; c < end; ++c) {
        int2 m = meta[c];
        unsigned rr = *(const unsigned*)(base + (unsigned)m.x);
        EDGE2(m.x, m.y, rr);
    }
    unsigned o = (unsigned)f2bf(a0) | ((unsigned)f2bf(a1) << 16);
    *(unsigned*)(svf + (size_t)n * DIM + lane * 2) = o;
}

// ---------------- GEMM+bias+ReLU via MFMA ----------------
__global__ __launch_bounds__(256) void gemm_kernel(
        const unsigned short* __restrict__ X,     // bf16 [N_PAD, DIM]
        const uint4* __restrict__ wfrag,          // [4][8][64] fragments
        const float* __restrict__ bias,
        unsigned short* __restrict__ out_bf,
        float* __restrict__ out_f,
        int last) {
    __shared__ uint4 wlds[2048];                  // 32 KB
    int tid = threadIdx.x;
    for (int i = tid; i < 2048; i += 256) wlds[i] = wfrag[i];

    int wv = tid >> 6, lane = tid & 63;
    int quad = lane >> 4, l16 = lane & 15;
    int row = blockIdx.x * 64 + wv * 16 + l16;

    f32x4 acc[8];
    #pragma unroll
    for (int i = 0; i < 8; ++i) acc[i] = (f32x4){0.f, 0.f, 0.f, 0.f};

    __syncthreads();

    const unsigned short* xp = X + (size_t)row * DIM + quad * 8;
    #pragma unroll
    for (int kk = 0; kk < 4; ++kk) {
        bf16x8 af = *(const bf16x8*)(xp + kk * 32);
        #pragma unroll
        for (int nt = 0; nt < 8; ++nt) {
            uint4 w = wlds[(kk * 8 + nt) * 64 + lane];
            bf16x8 bfr = __builtin_bit_cast(bf16x8, w);
            acc[nt] = __builtin_amdgcn_mfma_f32_16x16x32_bf16(af, bfr, acc[nt], 0, 0, 0);
        }
    }

    int orow0 = blockIdx.x * 64 + wv * 16 + quad * 4;
    #pragma unroll
    for (int nt = 0; nt < 8; ++nt) {
        int col = nt * 16 + l16;
        float b = bias[col];
        #pragma unroll
        for (int r = 0; r < 4; ++r) {
            int orow = orow0 + r;
            if (orow < N_NODES) {
                float val = fmaxf(acc[nt][r] + b, 0.f);
                if (last) out_f[(size_t)orow * DIM + col] = val;
                else      out_bf[(size_t)orow * DIM + col] = f2bf(val);
            }
        }
    }
}

// ---------------------------------------------------------------------------
extern "C" void kernel_launch(void* const* d_in, const int* in_sizes, int n_in,
                              void* d_out, int out_size, void* d_ws, size_t ws_size,
                              hipStream_t stream) {
    const float* v     = (const float*)d_in[0];
    const float* e     = (const float*)d_in[1];
    const int*   src   = (const int*)  d_in[2];
    const int*   dst   = (const int*)  d_in[3];
    const float* Aw    = (const float*)d_in[4];
    const float* Ab    = (const float*)d_in[5];
    const float* rs    = (const float*)d_in[6];
    const float* sigma = (const float*)d_in[7];
    float* out = (float*)d_out;

    // ---- workspace layout (~51.5 MB) ----
    char* p = (char*)d_ws;
    int2*           meta  = (int2*)p;            p += (size_t)N_EDGES * 8;       // 12.8 MB (final CSR)
    unsigned short* bufV  = (unsigned short*)p;  p += (size_t)N_PAD * DIM * 2;   // 12.81 MB (pristine bf16 v)
    unsigned short* bufA  = (unsigned short*)p;  p += (size_t)N_PAD * DIM * 2;   // 12.81 MB (gather out)
    unsigned short* bufB  = (unsigned short*)p;  p += (size_t)N_PAD * DIM * 2;   // 12.81 MB (gemm out)
    uint4*          wfrag = (uint4*)p;           p += 2048 * 16;                 //  32 KB
    int*            off   = (int*)p;             p += (size_t)(N_NODES + 1) * 4;
    int*            gtot  = (int*)p;             p += (NGROUP + 2) * 4;
    int*            goff  = (int*)p;             p += (NGROUP + 2) * 4;
    // aliases (dead before host buffer's first write):
    int2* metaT   = (int2*)bufA;                 // unsorted meta, dead after tagsort
    int*  partial = (int*)bufB;                  // NB_PRE*NGROUP*4 = 1.6 MB
    int*  pbase   = partial + NB_PRE * NGROUP;   // 1.6 MB, dead after reorder

    preA_kernel<<<NB_CONV + NB_WPREP + NB_PRE, 256, 0, stream>>>(
        v, bufV, Aw, wfrag, dst, partial);
    ktot_kernel<<<(NGROUP + 255) / 256, 256, 0, stream>>>(partial, gtot);
    kscan_kernel<<<1, 256, 0, stream>>>(gtot, goff);
    kbase_kernel<<<(NGROUP + 255) / 256, 256, 0, stream>>>(partial, goff, pbase);
    reorder_kernel<<<NB_PRE, 512, 0, stream>>>(e, src, dst, rs, sigma, pbase, metaT);
    tagsort_kernel<<<NGROUP, 256, 0, stream>>>(metaT, goff, meta, off);

    const int GB = N_NODES / 4;   // 12500 blocks, 4 waves each, no barrier
    const int MB = N_PAD / 64;    // 782 blocks

    // bufV holds bf16(v) for the skip in ALL layers and is never overwritten.
    // gemm outputs ping-pong through bufB only (dead after each gather reads it).
    // L0: gather(bufV)->bufA; gemm->bufB
    // L1: gather(bufB)->bufA; gemm->bufB
    // L2: gather(bufB)->bufA; gemm->out (fp32)
    gather_kernel<<<GB, 256, 0, stream>>>(bufV, bufV, meta, off, bufA);
    gemm_kernel<<<MB, 256, 0, stream>>>(bufA, wfrag, Ab, bufB, nullptr, 0);
    gather_kernel<<<GB, 256, 0, stream>>>(bufB, bufV, meta, off, bufA);
    gemm_kernel<<<MB, 256, 0, stream>>>(bufA, wfrag, Ab, bufB, nullptr, 0);
    gather_kernel<<<GB, 256, 0, stream>>>(bufB, bufV, meta, off, bufA);
    gemm_kernel<<<MB, 256, 0, stream>>>(bufA, wfrag, Ab, nullptr, out, 1);
}